// Round 4
// baseline (8558.232 us; speedup 1.0000x reference)
//
#include <hip/hip_runtime.h>
#include <hip/hip_bf16.h>

typedef __bf16 bf16;
typedef bf16 bf16x8 __attribute__((ext_vector_type(8)));
typedef float f32x4 __attribute__((ext_vector_type(4)));

#define MFMA16(a, b, c) __builtin_amdgcn_mfma_f32_16x16x32_bf16(a, b, c, 0, 0, 0)

// ---------------- sizes / workspace layout ----------------
// B=16, N=512, L=96, IE=64, OUT=96
#define W_SQ 0
#define W_SK 262144
#define W_SV 524288
#define W_TQ 786432
#define W_TK 790528
#define W_TV 794624
#define W_CQ 798720
#define W_CK 802816
#define W_CV 806912
#define W_OW 811008
#define W_END 1400832
#define OFF_WSB  0ull
#define OFF_TOUT 2801664ull        // t_out  [B][N][L][IE] fp32
#define OFF_ST   204128256ull      // s_T    [B][N][L][IE] bf16
#define OFF_COUT 304791552ull      // c_out  [B][N][IE*L]  bf16

// ---------------- K0: convert all weights to bf16 ----------------
__global__ __launch_bounds__(256) void k_cvt(
    const float* __restrict__ sq, const float* __restrict__ sk, const float* __restrict__ sv,
    const float* __restrict__ tq, const float* __restrict__ tk, const float* __restrict__ tv,
    const float* __restrict__ cq, const float* __restrict__ ck, const float* __restrict__ cv,
    const float* __restrict__ ow, bf16* __restrict__ dst)
{
    int idx = blockIdx.x * 256 + threadIdx.x;
    if (idx >= W_END) return;
    const float* s; int off;
    if (idx < W_TQ) {
        int w = idx >> 18; off = idx & 262143;
        s = (w == 0) ? sq : ((w == 1) ? sk : sv);
    } else if (idx < W_OW) {
        int t = (idx - W_TQ) >> 12; off = (idx - W_TQ) & 4095;
        s = (t == 0) ? tq : (t == 1) ? tk : (t == 2) ? tv : (t == 3) ? cq : (t == 4) ? ck : cv;
    } else {
        s = ow; off = idx - W_OW;
    }
    dst[idx] = (bf16)s[off];
}

// ---------------- K1: time attention + LN (VALU fp32 compute), one block per (b,n) ----------------
__global__ __launch_bounds__(256) void k_att_time(
    const float* __restrict__ x, const bf16* __restrict__ wsb,
    const float* __restrict__ qb, const float* __restrict__ kb, const float* __restrict__ vb,
    const float* __restrict__ lng, const float* __restrict__ lnb,
    const float* __restrict__ hw, const float* __restrict__ hb,
    float* __restrict__ tout)
{
    // memory map (54,272 B static):
    // r0 [0,26624):      qs[64][104], ks[64][104]  -> later lf[64][100] fp32
    // r1 [26624,40448):  xs[96][72]               -> later Ps[64][72]
    // r2 [40448,54272):  vt[96][72]
    __shared__ __align__(16) char smem_[54272];
    bf16  (*qs)[104] = (bf16(*)[104])smem_;
    bf16  (*ks)[104] = (bf16(*)[104])(smem_ + 13312);
    float (*lf)[100] = (float(*)[100])smem_;
    bf16  (*xs)[72]  = (bf16(*)[72])(smem_ + 26624);
    bf16  (*Ps)[72]  = (bf16(*)[72])(smem_ + 26624);
    bf16  (*vt)[72]  = (bf16(*)[72])(smem_ + 40448);

    const int tid = threadIdx.x;
    const int bn = blockIdx.x;

    const float* xp = x + (size_t)bn * 6144;
    for (int idx = tid; idx < 6144; idx += 256) xs[idx / 64][idx & 63] = (bf16)xp[idx];
    float hscale = hw[0] + hw[1] + hw[2] + hw[3] + hw[4] + hw[5] + hw[6] + hw[7];
    float hbias = hb[0];
    __syncthreads();

    const bf16* Wq = wsb + W_TQ;
    const bf16* Wk = wsb + W_TK;
    const bf16* Wv = wsb + W_TV;
    // ---- q,k,v convs (contraction over ie), fp32 VALU
    for (int s = 0; s < 24; ++s) {
        int o = s * 256 + tid; int io = o / 96, l = o - io * 96;
        float aq = qb[io], ak = kb[io], av = vb[io];
        for (int c8 = 0; c8 < 8; ++c8) {
            bf16x8 xv = *(const bf16x8*)&xs[l][c8 * 8];
            bf16x8 wq = *(const bf16x8*)(Wq + io * 64 + c8 * 8);
            bf16x8 wk = *(const bf16x8*)(Wk + io * 64 + c8 * 8);
            bf16x8 wv = *(const bf16x8*)(Wv + io * 64 + c8 * 8);
            #pragma unroll
            for (int j = 0; j < 8; ++j) {
                float xf = (float)xv[j];
                aq += (float)wq[j] * xf; ak += (float)wk[j] * xf; av += (float)wv[j] * xf;
            }
        }
        qs[io][l] = (bf16)aq; ks[io][l] = (bf16)ak; vt[l][io] = (bf16)av;
    }
    __syncthreads();
    // ---- S = q @ k^T over l (logits into Ps)
    for (int s = 0; s < 16; ++s) {
        int o = s * 256 + tid; int i = o >> 6, j = o & 63;
        float acc = 0.f;
        for (int c8 = 0; c8 < 12; ++c8) {
            bf16x8 qv = *(const bf16x8*)&qs[i][c8 * 8];
            bf16x8 kv = *(const bf16x8*)&ks[j][c8 * 8];
            #pragma unroll
            for (int t = 0; t < 8; ++t) acc += (float)qv[t] * (float)kv[t];
        }
        Ps[i][j] = (bf16)acc;
    }
    __syncthreads();
    // ---- softmax rows (wave 0), logits/sqrt(8)
    if (tid < 64) {
        const float inv_kd = 0.35355339059327379f;
        int i = tid; float m = -1e30f;
        for (int j = 0; j < 64; ++j) m = fmaxf(m, (float)Ps[i][j]);
        float ssum = 0.f;
        for (int j = 0; j < 64; ++j) { float e = __expf(((float)Ps[i][j] - m) * inv_kd); ssum += e; Ps[i][j] = (bf16)e; }
        float rc = 1.f / ssum;
        for (int j = 0; j < 64; ++j) Ps[i][j] = (bf16)((float)Ps[i][j] * rc);
    }
    __syncthreads();
    // ---- line = P @ v
    for (int s = 0; s < 24; ++s) {
        int o = s * 256 + tid; int i = o / 96, l = o - i * 96;
        float acc = 0.f;
        for (int c8 = 0; c8 < 8; ++c8) {
            bf16x8 pv = *(const bf16x8*)&Ps[i][c8 * 8];
            bf16x8 vv = *(const bf16x8*)&vt[l][c8 * 8];
            #pragma unroll
            for (int t = 0; t < 8; ++t) acc += (float)pv[t] * (float)vv[t];
        }
        lf[i][l] = acc;
    }
    __syncthreads();
    // ---- residual (fp32 x) + LayerNorm over l; coalesced fp32 store
    if (tid < 64) {
        int i = tid;
        float s1 = 0.f, s2 = 0.f;
        for (int l = 0; l < 96; ++l) {
            float h = xp[l * 64 + i] + (lf[i][l] * hscale + hbias);
            s1 += h; s2 += h * h;
        }
        float mean = s1 * (1.f / 96.f);
        float var = s2 * (1.f / 96.f) - mean * mean;
        float rs = rsqrtf(var + 1e-5f);
        float* dst = tout + (size_t)bn * 6144;
        for (int l = 0; l < 96; ++l) {
            float h = xp[l * 64 + i] + (lf[i][l] * hscale + hbias);
            dst[l * 64 + i] = (h - mean) * rs * lng[l] + lnb[l];
        }
    }
}

// ---------------- K2: space attention (VALU fp32 compute), one block per (b,l) ----------------
__global__ __launch_bounds__(256) void k_att_space(
    const float* __restrict__ x, const bf16* __restrict__ wsb,
    const float* __restrict__ qb, const float* __restrict__ kb, const float* __restrict__ vb,
    const float* __restrict__ hw, const float* __restrict__ hb,
    bf16* __restrict__ sT)
{
    extern __shared__ char smem[];
    bf16 (*xs)[520] = (bf16(*)[520])smem;               // 66,560 B  xs[ie][n]
    bf16 (*qc)[72] = (bf16(*)[72])(smem + 66560);       //  9,216 B  q chunk [i][n'] (vtc overlay)
    bf16 (*kc)[72] = (bf16(*)[72])(smem + 75776);       //  9,216 B  k chunk [j][n']
    bf16 (*wt)[136] = (bf16(*)[136])(smem + 84992);     // 17,408 B  weight tile [64][128] (tt overlay)
    bf16 (*Ps)[72] = (bf16(*)[72])(smem + 102400);      //  9,216 B  P [i][j]
    bf16 (*vtc)[72] = qc;
    bf16 (*tt)[72] = (bf16(*)[72])wt;

    const int tid = threadIdx.x;
    const int b = blockIdx.x / 96, l = blockIdx.x % 96;
    const int tr = tid >> 4, tc = tid & 15;   // 4x4 output tile: rows tr*4+d, cols tc+16*d

    {
        const float* xb = x + ((size_t)b * 512 * 96 + l) * 64;
        for (int idx = tid; idx < 512 * 64; idx += 256) {
            int n = idx >> 6, ie = idx & 63;
            xs[ie][n] = (bf16)xb[(size_t)n * 6144 + ie];
        }
    }
    float hscale = hw[0] + hw[1] + hw[2] + hw[3] + hw[4] + hw[5] + hw[6] + hw[7];
    float hbias = hb[0];
    __syncthreads();

    const bf16* Wq = wsb + W_SQ;
    const bf16* Wk = wsb + W_SK;
    const bf16* Wv = wsb + W_SV;

    float sac[16];
    #pragma unroll
    for (int t = 0; t < 16; ++t) sac[t] = 0.f;

    for (int nqc = 0; nqc < 8; ++nqc) {
        // ---- q chunk: qc[i][n'-local], K=512
        {
            float pacc[16];
            #pragma unroll
            for (int t = 0; t < 16; ++t) pacc[t] = 0.f;
            for (int kt = 0; kt < 4; ++kt) {
                for (int idx = tid; idx < 4096; idx += 256) {
                    int rr = idx >> 6, j = idx & 63;
                    *(uint*)&wt[rr][2 * j] = *(const uint*)(Wq + (size_t)(nqc * 64 + rr) * 512 + kt * 128 + 2 * j);
                }
                __syncthreads();
                for (int k8 = 0; k8 < 16; ++k8) {
                    bf16x8 a0 = *(const bf16x8*)&xs[tr * 4 + 0][kt * 128 + k8 * 8];
                    bf16x8 a1 = *(const bf16x8*)&xs[tr * 4 + 1][kt * 128 + k8 * 8];
                    bf16x8 a2 = *(const bf16x8*)&xs[tr * 4 + 2][kt * 128 + k8 * 8];
                    bf16x8 a3 = *(const bf16x8*)&xs[tr * 4 + 3][kt * 128 + k8 * 8];
                    bf16x8 b0 = *(const bf16x8*)&wt[tc + 0][k8 * 8];
                    bf16x8 b1 = *(const bf16x8*)&wt[tc + 16][k8 * 8];
                    bf16x8 b2 = *(const bf16x8*)&wt[tc + 32][k8 * 8];
                    bf16x8 b3 = *(const bf16x8*)&wt[tc + 48][k8 * 8];
                    #pragma unroll
                    for (int t = 0; t < 8; ++t) {
                        float bv0 = (float)b0[t], bv1 = (float)b1[t], bv2 = (float)b2[t], bv3 = (float)b3[t];
                        float av0 = (float)a0[t], av1 = (float)a1[t], av2 = (float)a2[t], av3 = (float)a3[t];
                        pacc[0] += av0 * bv0; pacc[1] += av0 * bv1; pacc[2] += av0 * bv2; pacc[3] += av0 * bv3;
                        pacc[4] += av1 * bv0; pacc[5] += av1 * bv1; pacc[6] += av1 * bv2; pacc[7] += av1 * bv3;
                        pacc[8] += av2 * bv0; pacc[9] += av2 * bv1; pacc[10] += av2 * bv2; pacc[11] += av2 * bv3;
                        pacc[12] += av3 * bv0; pacc[13] += av3 * bv1; pacc[14] += av3 * bv2; pacc[15] += av3 * bv3;
                    }
                }
                __syncthreads();
            }
            #pragma unroll
            for (int di = 0; di < 4; ++di)
                #pragma unroll
                for (int dn = 0; dn < 4; ++dn)
                    qc[tr * 4 + di][tc + 16 * dn] = (bf16)(pacc[di * 4 + dn] + qb[nqc * 64 + tc + 16 * dn]);
        }
        // ---- k chunk
        {
            float pacc[16];
            #pragma unroll
            for (int t = 0; t < 16; ++t) pacc[t] = 0.f;
            for (int kt = 0; kt < 4; ++kt) {
                for (int idx = tid; idx < 4096; idx += 256) {
                    int rr = idx >> 6, j = idx & 63;
                    *(uint*)&wt[rr][2 * j] = *(const uint*)(Wk + (size_t)(nqc * 64 + rr) * 512 + kt * 128 + 2 * j);
                }
                __syncthreads();
                for (int k8 = 0; k8 < 16; ++k8) {
                    bf16x8 a0 = *(const bf16x8*)&xs[tr * 4 + 0][kt * 128 + k8 * 8];
                    bf16x8 a1 = *(const bf16x8*)&xs[tr * 4 + 1][kt * 128 + k8 * 8];
                    bf16x8 a2 = *(const bf16x8*)&xs[tr * 4 + 2][kt * 128 + k8 * 8];
                    bf16x8 a3 = *(const bf16x8*)&xs[tr * 4 + 3][kt * 128 + k8 * 8];
                    bf16x8 b0 = *(const bf16x8*)&wt[tc + 0][k8 * 8];
                    bf16x8 b1 = *(const bf16x8*)&wt[tc + 16][k8 * 8];
                    bf16x8 b2 = *(const bf16x8*)&wt[tc + 32][k8 * 8];
                    bf16x8 b3 = *(const bf16x8*)&wt[tc + 48][k8 * 8];
                    #pragma unroll
                    for (int t = 0; t < 8; ++t) {
                        float bv0 = (float)b0[t], bv1 = (float)b1[t], bv2 = (float)b2[t], bv3 = (float)b3[t];
                        float av0 = (float)a0[t], av1 = (float)a1[t], av2 = (float)a2[t], av3 = (float)a3[t];
                        pacc[0] += av0 * bv0; pacc[1] += av0 * bv1; pacc[2] += av0 * bv2; pacc[3] += av0 * bv3;
                        pacc[4] += av1 * bv0; pacc[5] += av1 * bv1; pacc[6] += av1 * bv2; pacc[7] += av1 * bv3;
                        pacc[8] += av2 * bv0; pacc[9] += av2 * bv1; pacc[10] += av2 * bv2; pacc[11] += av2 * bv3;
                        pacc[12] += av3 * bv0; pacc[13] += av3 * bv1; pacc[14] += av3 * bv2; pacc[15] += av3 * bv3;
                    }
                }
                __syncthreads();
            }
            #pragma unroll
            for (int di = 0; di < 4; ++di)
                #pragma unroll
                for (int dn = 0; dn < 4; ++dn)
                    kc[tr * 4 + di][tc + 16 * dn] = (bf16)(pacc[di * 4 + dn] + kb[nqc * 64 + tc + 16 * dn]);
        }
        __syncthreads();
        // ---- S += qc @ kc^T over this n' chunk
        for (int k8 = 0; k8 < 8; ++k8) {
            bf16x8 a0 = *(const bf16x8*)&qc[tr * 4 + 0][k8 * 8];
            bf16x8 a1 = *(const bf16x8*)&qc[tr * 4 + 1][k8 * 8];
            bf16x8 a2 = *(const bf16x8*)&qc[tr * 4 + 2][k8 * 8];
            bf16x8 a3 = *(const bf16x8*)&qc[tr * 4 + 3][k8 * 8];
            bf16x8 b0 = *(const bf16x8*)&kc[tc + 0][k8 * 8];
            bf16x8 b1 = *(const bf16x8*)&kc[tc + 16][k8 * 8];
            bf16x8 b2 = *(const bf16x8*)&kc[tc + 32][k8 * 8];
            bf16x8 b3 = *(const bf16x8*)&kc[tc + 48][k8 * 8];
            #pragma unroll
            for (int t = 0; t < 8; ++t) {
                float bv0 = (float)b0[t], bv1 = (float)b1[t], bv2 = (float)b2[t], bv3 = (float)b3[t];
                float av0 = (float)a0[t], av1 = (float)a1[t], av2 = (float)a2[t], av3 = (float)a3[t];
                sac[0] += av0 * bv0; sac[1] += av0 * bv1; sac[2] += av0 * bv2; sac[3] += av0 * bv3;
                sac[4] += av1 * bv0; sac[5] += av1 * bv1; sac[6] += av1 * bv2; sac[7] += av1 * bv3;
                sac[8] += av2 * bv0; sac[9] += av2 * bv1; sac[10] += av2 * bv2; sac[11] += av2 * bv3;
                sac[12] += av3 * bv0; sac[13] += av3 * bv1; sac[14] += av3 * bv2; sac[15] += av3 * bv3;
            }
        }
        __syncthreads();
    }
    // ---- softmax (rows i = tr*4+di, cols j = tc+16*dj across 16-lane group), logits/8
    #pragma unroll
    for (int di = 0; di < 4; ++di) {
        float m = fmaxf(fmaxf(sac[di * 4 + 0], sac[di * 4 + 1]), fmaxf(sac[di * 4 + 2], sac[di * 4 + 3]));
        for (int msk = 1; msk < 16; msk <<= 1) m = fmaxf(m, __shfl_xor(m, msk, 64));
        float e0 = __expf((sac[di * 4 + 0] - m) * 0.125f);
        float e1 = __expf((sac[di * 4 + 1] - m) * 0.125f);
        float e2 = __expf((sac[di * 4 + 2] - m) * 0.125f);
        float e3 = __expf((sac[di * 4 + 3] - m) * 0.125f);
        float s = e0 + e1 + e2 + e3;
        for (int msk = 1; msk < 16; msk <<= 1) s += __shfl_xor(s, msk, 64);
        float rc = 1.f / s;
        Ps[tr * 4 + di][tc + 0]  = (bf16)(e0 * rc);
        Ps[tr * 4 + di][tc + 16] = (bf16)(e1 * rc);
        Ps[tr * 4 + di][tc + 32] = (bf16)(e2 * rc);
        Ps[tr * 4 + di][tc + 48] = (bf16)(e3 * rc);
    }
    __syncthreads();
    // ---- PV per 64-col chunk; fused transpose store to s_T[b][n][l][ie]
    for (int nc = 0; nc < 8; ++nc) {
        {   // v chunk -> vtc[n-local][j]
            float pacc[16];
            #pragma unroll
            for (int t = 0; t < 16; ++t) pacc[t] = 0.f;
            for (int kt = 0; kt < 4; ++kt) {
                for (int idx = tid; idx < 4096; idx += 256) {
                    int rr = idx >> 6, j = idx & 63;
                    *(uint*)&wt[rr][2 * j] = *(const uint*)(Wv + (size_t)(nc * 64 + rr) * 512 + kt * 128 + 2 * j);
                }
                __syncthreads();
                for (int k8 = 0; k8 < 16; ++k8) {
                    bf16x8 a0 = *(const bf16x8*)&xs[tr * 4 + 0][kt * 128 + k8 * 8];
                    bf16x8 a1 = *(const bf16x8*)&xs[tr * 4 + 1][kt * 128 + k8 * 8];
                    bf16x8 a2 = *(const bf16x8*)&xs[tr * 4 + 2][kt * 128 + k8 * 8];
                    bf16x8 a3 = *(const bf16x8*)&xs[tr * 4 + 3][kt * 128 + k8 * 8];
                    bf16x8 b0 = *(const bf16x8*)&wt[tc + 0][k8 * 8];
                    bf16x8 b1 = *(const bf16x8*)&wt[tc + 16][k8 * 8];
                    bf16x8 b2 = *(const bf16x8*)&wt[tc + 32][k8 * 8];
                    bf16x8 b3 = *(const bf16x8*)&wt[tc + 48][k8 * 8];
                    #pragma unroll
                    for (int t = 0; t < 8; ++t) {
                        float bv0 = (float)b0[t], bv1 = (float)b1[t], bv2 = (float)b2[t], bv3 = (float)b3[t];
                        float av0 = (float)a0[t], av1 = (float)a1[t], av2 = (float)a2[t], av3 = (float)a3[t];
                        pacc[0] += av0 * bv0; pacc[1] += av0 * bv1; pacc[2] += av0 * bv2; pacc[3] += av0 * bv3;
                        pacc[4] += av1 * bv0; pacc[5] += av1 * bv1; pacc[6] += av1 * bv2; pacc[7] += av1 * bv3;
                        pacc[8] += av2 * bv0; pacc[9] += av2 * bv1; pacc[10] += av2 * bv2; pacc[11] += av2 * bv3;
                        pacc[12] += av3 * bv0; pacc[13] += av3 * bv1; pacc[14] += av3 * bv2; pacc[15] += av3 * bv3;
                    }
                }
                __syncthreads();
            }
            #pragma unroll
            for (int di = 0; di < 4; ++di)
                #pragma unroll
                for (int dn = 0; dn < 4; ++dn)
                    vtc[tc + 16 * dn][tr * 4 + di] = (bf16)(pacc[di * 4 + dn] + vb[nc * 64 + tc + 16 * dn]);
        }
        __syncthreads();
        // line chunk = P @ v_c -> tt[n-local][i]
        {
            float oc[16];
            #pragma unroll
            for (int t = 0; t < 16; ++t) oc[t] = 0.f;
            for (int k8 = 0; k8 < 8; ++k8) {
                bf16x8 a0 = *(const bf16x8*)&Ps[tr * 4 + 0][k8 * 8];
                bf16x8 a1 = *(const bf16x8*)&Ps[tr * 4 + 1][k8 * 8];
                bf16x8 a2 = *(const bf16x8*)&Ps[tr * 4 + 2][k8 * 8];
                bf16x8 a3 = *(const bf16x8*)&Ps[tr * 4 + 3][k8 * 8];
                bf16x8 b0 = *(const bf16x8*)&vtc[tc + 0][k8 * 8];
                bf16x8 b1 = *(const bf16x8*)&vtc[tc + 16][k8 * 8];
                bf16x8 b2 = *(const bf16x8*)&vtc[tc + 32][k8 * 8];
                bf16x8 b3 = *(const bf16x8*)&vtc[tc + 48][k8 * 8];
                #pragma unroll
                for (int t = 0; t < 8; ++t) {
                    float bv0 = (float)b0[t], bv1 = (float)b1[t], bv2 = (float)b2[t], bv3 = (float)b3[t];
                    float av0 = (float)a0[t], av1 = (float)a1[t], av2 = (float)a2[t], av3 = (float)a3[t];
                    oc[0] += av0 * bv0; oc[1] += av0 * bv1; oc[2] += av0 * bv2; oc[3] += av0 * bv3;
                    oc[4] += av1 * bv0; oc[5] += av1 * bv1; oc[6] += av1 * bv2; oc[7] += av1 * bv3;
                    oc[8] += av2 * bv0; oc[9] += av2 * bv1; oc[10] += av2 * bv2; oc[11] += av2 * bv3;
                    oc[12] += av3 * bv0; oc[13] += av3 * bv1; oc[14] += av3 * bv2; oc[15] += av3 * bv3;
                }
            }
            __syncthreads();
            #pragma unroll
            for (int di = 0; di < 4; ++di)
                #pragma unroll
                for (int dn = 0; dn < 4; ++dn)
                    tt[tc + 16 * dn][tr * 4 + di] = (bf16)(oc[di * 4 + dn] * hscale + hbias);
        }
        __syncthreads();
        for (int idx = tid; idx < 2048; idx += 256) {
            int n = idx >> 5, p = idx & 31;
            *(uint*)(sT + ((size_t)(b * 512 + nc * 64 + n) * 96 + l) * 64 + 2 * p) = *(const uint*)&tt[n][2 * p];
        }
        __syncthreads();
    }
}

// ---------------- K3: cross attention + LN (VALU fp32 compute), one block per (b,n) ----------------
__global__ __launch_bounds__(256) void k_att_cross(
    const float* __restrict__ tin, const bf16* __restrict__ sin, const bf16* __restrict__ wsb,
    const float* __restrict__ qb, const float* __restrict__ kb, const float* __restrict__ vb,
    const float* __restrict__ lng, const float* __restrict__ lnb,
    const float* __restrict__ hw, const float* __restrict__ hb,
    bf16* __restrict__ cout)
{
    // r0 [0,26624):      qs[64][104], ks[64][104] -> lf[64][100] fp32
    // r1 [26624,40448):  ts[96][72] -> Ps[64][72] -> cs[64][104]
    // r2 [40448,54272):  ss[96][72] -> vt[96][72]
    __shared__ __align__(16) char smem_[54272];
    bf16  (*qs)[104] = (bf16(*)[104])smem_;
    bf16  (*ks)[104] = (bf16(*)[104])(smem_ + 13312);
    float (*lf)[100] = (float(*)[100])smem_;
    bf16  (*ts)[72]  = (bf16(*)[72])(smem_ + 26624);
    bf16  (*Ps)[72]  = (bf16(*)[72])(smem_ + 26624);
    bf16  (*cs)[104] = (bf16(*)[104])(smem_ + 26624);
    bf16  (*ss)[72]  = (bf16(*)[72])(smem_ + 40448);
    bf16  (*vt)[72]  = (bf16(*)[72])(smem_ + 40448);

    const int tid = threadIdx.x;
    const int bn = blockIdx.x;

    const float* tf = tin + (size_t)bn * 6144;
    const uint* ssrc = (const uint*)(sin + (size_t)bn * 6144);
    for (int idx = tid; idx < 3072; idx += 256) {
        int l = idx >> 5, p = idx & 31;
        *(uint*)&ss[l][2 * p] = ssrc[idx];
    }
    for (int idx = tid; idx < 6144; idx += 256) ts[idx / 64][idx & 63] = (bf16)tf[idx];
    float hscale = hw[0] + hw[1] + hw[2] + hw[3] + hw[4] + hw[5] + hw[6] + hw[7];
    float hbias = hb[0];
    __syncthreads();

    const bf16* Wq = wsb + W_CQ;
    const bf16* Wk = wsb + W_CK;
    const bf16* Wv = wsb + W_CV;
    // ---- q conv from s slice
    for (int s = 0; s < 24; ++s) {
        int o = s * 256 + tid; int io = o / 96, l = o - io * 96;
        float aq = qb[io];
        for (int c8 = 0; c8 < 8; ++c8) {
            bf16x8 xv = *(const bf16x8*)&ss[l][c8 * 8];
            bf16x8 wq = *(const bf16x8*)(Wq + io * 64 + c8 * 8);
            #pragma unroll
            for (int j = 0; j < 8; ++j) aq += (float)wq[j] * (float)xv[j];
        }
        qs[io][l] = (bf16)aq;
    }
    __syncthreads();   // ss dead; vt may be written
    // ---- k, v convs from t slice (v transposed into vt over ss)
    for (int s = 0; s < 24; ++s) {
        int o = s * 256 + tid; int io = o / 96, l = o - io * 96;
        float ak = kb[io], av = vb[io];
        for (int c8 = 0; c8 < 8; ++c8) {
            bf16x8 xv = *(const bf16x8*)&ts[l][c8 * 8];
            bf16x8 wk = *(const bf16x8*)(Wk + io * 64 + c8 * 8);
            bf16x8 wv = *(const bf16x8*)(Wv + io * 64 + c8 * 8);
            #pragma unroll
            for (int j = 0; j < 8; ++j) {
                float xf = (float)xv[j];
                ak += (float)wk[j] * xf; av += (float)wv[j] * xf;
            }
        }
        ks[io][l] = (bf16)ak; vt[l][io] = (bf16)av;
    }
    __syncthreads();   // ts dead after this point (residual uses tf global); Ps may be written
    // ---- S = q @ k^T over l
    for (int s = 0; s < 16; ++s) {
        int o = s * 256 + tid; int i = o >> 6, j = o & 63;
        float acc = 0.f;
        for (int c8 = 0; c8 < 12; ++c8) {
            bf16x8 qv = *(const bf16x8*)&qs[i][c8 * 8];
            bf16x8 kv = *(const bf16x8*)&ks[j][c8 * 8];
            #pragma unroll
            for (int t = 0; t < 8; ++t) acc += (float)qv[t] * (float)kv[t];
        }
        Ps[i][j] = (bf16)acc;
    }
    __syncthreads();
    // ---- softmax rows (wave 0)
    if (tid < 64) {
        const float inv_kd = 0.35355339059327379f;
        int i = tid; float m = -1e30f;
        for (int j = 0; j < 64; ++j) m = fmaxf(m, (float)Ps[i][j]);
        float ssum = 0.f;
        for (int j = 0; j < 64; ++j) { float e = __expf(((float)Ps[i][j] - m) * inv_kd); ssum += e; Ps[i][j] = (bf16)e; }
        float rc = 1.f / ssum;
        for (int j = 0; j < 64; ++j) Ps[i][j] = (bf16)((float)Ps[i][j] * rc);
    }
    __syncthreads();
    // ---- line = P @ v
    for (int s = 0; s < 24; ++s) {
        int o = s * 256 + tid; int i = o / 96, l = o - i * 96;
        float acc = 0.f;
        for (int c8 = 0; c8 < 8; ++c8) {
            bf16x8 pv = *(const bf16x8*)&Ps[i][c8 * 8];
            bf16x8 vv = *(const bf16x8*)&vt[l][c8 * 8];
            #pragma unroll
            for (int t = 0; t < 8; ++t) acc += (float)pv[t] * (float)vv[t];
        }
        lf[i][l] = acc;
    }
    __syncthreads();
    // ---- residual (fp32 t_out) + LN over l -> cs[i][l] (Ps region dead)
    if (tid < 64) {
        int i = tid;
        float s1 = 0.f, s2 = 0.f;
        for (int l = 0; l < 96; ++l) {
            float h = tf[l * 64 + i] + (lf[i][l] * hscale + hbias);
            s1 += h; s2 += h * h;
        }
        float mean = s1 * (1.f / 96.f);
        float var = s2 * (1.f / 96.f) - mean * mean;
        float rs = rsqrtf(var + 1e-5f);
        for (int l = 0; l < 96; ++l) {
            float h = tf[l * 64 + i] + (lf[i][l] * hscale + hbias);
            cs[i][l] = (bf16)((h - mean) * rs * lng[l] + lnb[l]);
        }
    }
    __syncthreads();
    uint* dst = (uint*)(cout + (size_t)bn * 6144);
    for (int idx = tid; idx < 3072; idx += 256) {
        int i = idx / 48, p = idx % 48;
        dst[idx] = *(const uint*)&cs[i][2 * p];
    }
}

// ---------------- K4: final GEMM [8192 x 96 x 6144] (MFMA, proven) ----------------
__global__ __launch_bounds__(256) void k_final(
    const bf16* __restrict__ cin, const bf16* __restrict__ wsb,
    const float* __restrict__ ob, float* __restrict__ out)
{
    __shared__ bf16 At[64][136];
    __shared__ bf16 Wt[96][136];
    const int tid = threadIdx.x;
    const int r0 = blockIdx.x * 64;
    const int lane = tid & 63, w = tid >> 6, lrow = lane & 15, lgrp = lane >> 4;
    const int row0 = w * 16;
    const bf16* Wo = wsb + W_OW;

    f32x4 acc[6];
    for (int cf = 0; cf < 6; ++cf) acc[cf] = (f32x4){0.f, 0.f, 0.f, 0.f};
    for (int kt = 0; kt < 48; ++kt) {
        for (int idx = tid; idx < 4096; idx += 256) {
            int rr = idx >> 6, j = idx & 63;
            *(uint*)&At[rr][2 * j] = *(const uint*)(cin + (size_t)(r0 + rr) * 6144 + kt * 128 + 2 * j);
        }
        for (int idx = tid; idx < 6144; idx += 256) {
            int rr = idx >> 6, j = idx & 63;
            *(uint*)&Wt[rr][2 * j] = *(const uint*)(Wo + (size_t)rr * 6144 + kt * 128 + 2 * j);
        }
        __syncthreads();
        for (int ks_ = 0; ks_ < 4; ++ks_) {
            bf16x8 a = *(const bf16x8*)&At[row0 + lrow][ks_ * 32 + lgrp * 8];
            for (int cf = 0; cf < 6; ++cf)
                acc[cf] = MFMA16(a, *(const bf16x8*)&Wt[cf * 16 + lrow][ks_ * 32 + lgrp * 8], acc[cf]);
        }
        __syncthreads();
    }
    for (int cf = 0; cf < 6; ++cf)
        for (int r = 0; r < 4; ++r) {
            int row = r0 + row0 + lgrp * 4 + r, col = cf * 16 + lrow;
            out[(size_t)row * 96 + col] = acc[cf][r] + ob[col];
        }
}

// ---------------- host ----------------
extern "C" void kernel_launch(void* const* d_in, const int* in_sizes, int n_in,
                              void* d_out, int out_size, void* d_ws, size_t ws_size,
                              hipStream_t stream)
{
    const float* x = (const float*)d_in[0];
    const float* tq_w = (const float*)d_in[1];  const float* tq_b = (const float*)d_in[2];
    const float* tk_w = (const float*)d_in[3];  const float* tk_b = (const float*)d_in[4];
    const float* tv_w = (const float*)d_in[5];  const float* tv_b = (const float*)d_in[6];
    const float* t_ln_w = (const float*)d_in[7];  const float* t_ln_b = (const float*)d_in[8];
    const float* t_hw = (const float*)d_in[9];  const float* t_hb = (const float*)d_in[10];
    const float* sq_w = (const float*)d_in[11]; const float* sq_b = (const float*)d_in[12];
    const float* sk_w = (const float*)d_in[13]; const float* sk_b = (const float*)d_in[14];
    const float* sv_w = (const float*)d_in[15]; const float* sv_b = (const float*)d_in[16];
    const float* s_hw = (const float*)d_in[17]; const float* s_hb = (const float*)d_in[18];
    const float* cq_w = (const float*)d_in[19]; const float* cq_b = (const float*)d_in[20];
    const float* ck_w = (const float*)d_in[21]; const float* ck_b = (const float*)d_in[22];
    const float* cv_w = (const float*)d_in[23]; const float* cv_b = (const float*)d_in[24];
    const float* c_ln_w = (const float*)d_in[25]; const float* c_ln_b = (const float*)d_in[26];
    const float* c_hw = (const float*)d_in[27]; const float* c_hb = (const float*)d_in[28];
    const float* out_w = (const float*)d_in[29]; const float* out_b = (const float*)d_in[30];

    char* ws = (char*)d_ws;
    bf16*  wsb  = (bf16*)(ws + OFF_WSB);
    float* tout = (float*)(ws + OFF_TOUT);
    bf16*  sT   = (bf16*)(ws + OFF_ST);
    bf16*  cout = (bf16*)(ws + OFF_COUT);

    hipFuncSetAttribute((const void*)k_att_space, hipFuncAttributeMaxDynamicSharedMemorySize, 111616);

    k_cvt<<<W_END / 256, 256, 0, stream>>>(sq_w, sk_w, sv_w, tq_w, tk_w, tv_w, cq_w, ck_w, cv_w, out_w, wsb);
    k_att_time<<<8192, 256, 0, stream>>>(x, wsb, tq_b, tk_b, tv_b, t_ln_w, t_ln_b, t_hw, t_hb, tout);
    k_att_space<<<1536, 256, 111616, stream>>>(x, wsb, sq_b, sk_b, sv_b, s_hw, s_hb, sT);
    k_att_cross<<<8192, 256, 0, stream>>>(tout, sT, wsb, cq_b, ck_b, cv_b, c_ln_w, c_ln_b, c_hw, c_hb, cout);
    k_final<<<128, 256, 0, stream>>>(cout, wsb, out_b, (float*)d_out);
}

// Round 5
// 4996.580 us; speedup vs baseline: 1.7128x; 1.7128x over previous
//
#include <hip/hip_runtime.h>
#include <hip/hip_bf16.h>

typedef __bf16 bf16;
typedef bf16 bf16x8 __attribute__((ext_vector_type(8)));
typedef float f32x4 __attribute__((ext_vector_type(4)));

#define MFMA16(a, b, c) __builtin_amdgcn_mfma_f32_16x16x32_bf16(a, b, c, 0, 0, 0)

// ---------------- sizes / workspace layout ----------------
// B=16, N=512, L=96, IE=64, OUT=96
#define W_SQ 0
#define W_SK 262144
#define W_SV 524288
#define W_TQ 786432
#define W_TK 790528
#define W_TV 794624
#define W_CQ 798720
#define W_CK 802816
#define W_CV 806912
#define W_OW 811008
#define W_END 1400832
#define OFF_WSB  0ull
#define OFF_TOUT 2801664ull        // t_out  [B][N][L][IE] fp32
#define OFF_ST   204128256ull      // s_T    [B][N][L][IE] bf16
#define OFF_COUT 304791552ull      // c_out  [B][N][IE*L]  bf16

// ---------------- K0: convert all weights to bf16 ----------------
__global__ __launch_bounds__(256) void k_cvt(
    const float* __restrict__ sq, const float* __restrict__ sk, const float* __restrict__ sv,
    const float* __restrict__ tq, const float* __restrict__ tk, const float* __restrict__ tv,
    const float* __restrict__ cq, const float* __restrict__ ck, const float* __restrict__ cv,
    const float* __restrict__ ow, bf16* __restrict__ dst)
{
    int idx = blockIdx.x * 256 + threadIdx.x;
    if (idx >= W_END) return;
    const float* s; int off;
    if (idx < W_TQ) {
        int w = idx >> 18; off = idx & 262143;
        s = (w == 0) ? sq : ((w == 1) ? sk : sv);
    } else if (idx < W_OW) {
        int t = (idx - W_TQ) >> 12; off = (idx - W_TQ) & 4095;
        s = (t == 0) ? tq : (t == 1) ? tk : (t == 2) ? tv : (t == 3) ? cq : (t == 4) ? ck : cv;
    } else {
        s = ow; off = idx - W_OW;
    }
    dst[idx] = (bf16)s[off];
}

// ---------------- K1: time attention + LN (VALU fp32 compute), one block per (b,n) ----------------
__global__ __launch_bounds__(256) void k_att_time(
    const float* __restrict__ x, const bf16* __restrict__ wsb,
    const float* __restrict__ qb, const float* __restrict__ kb, const float* __restrict__ vb,
    const float* __restrict__ lng, const float* __restrict__ lnb,
    const float* __restrict__ hw, const float* __restrict__ hb,
    float* __restrict__ tout)
{
    // memory map (54,272 B static):
    // r0 [0,26624):      qs[64][104], ks[64][104]  -> later lf[64][100] fp32
    // r1 [26624,40448):  xs[96][72]               -> later Ps[64][72]
    // r2 [40448,54272):  vt[96][72]
    __shared__ __align__(16) char smem_[54272];
    bf16  (*qs)[104] = (bf16(*)[104])smem_;
    bf16  (*ks)[104] = (bf16(*)[104])(smem_ + 13312);
    float (*lf)[100] = (float(*)[100])smem_;
    bf16  (*xs)[72]  = (bf16(*)[72])(smem_ + 26624);
    bf16  (*Ps)[72]  = (bf16(*)[72])(smem_ + 26624);
    bf16  (*vt)[72]  = (bf16(*)[72])(smem_ + 40448);

    const int tid = threadIdx.x;
    const int bn = blockIdx.x;

    const float* xp = x + (size_t)bn * 6144;
    for (int idx = tid; idx < 6144; idx += 256) xs[idx / 64][idx & 63] = (bf16)xp[idx];
    float hscale = hw[0] + hw[1] + hw[2] + hw[3] + hw[4] + hw[5] + hw[6] + hw[7];
    float hbias = hb[0];
    __syncthreads();

    const bf16* Wq = wsb + W_TQ;
    const bf16* Wk = wsb + W_TK;
    const bf16* Wv = wsb + W_TV;
    // ---- q,k,v convs (contraction over ie), fp32 VALU
    for (int s = 0; s < 24; ++s) {
        int o = s * 256 + tid; int io = o / 96, l = o - io * 96;
        float aq = qb[io], ak = kb[io], av = vb[io];
        for (int c8 = 0; c8 < 8; ++c8) {
            bf16x8 xv = *(const bf16x8*)&xs[l][c8 * 8];
            bf16x8 wq = *(const bf16x8*)(Wq + io * 64 + c8 * 8);
            bf16x8 wk = *(const bf16x8*)(Wk + io * 64 + c8 * 8);
            bf16x8 wv = *(const bf16x8*)(Wv + io * 64 + c8 * 8);
            #pragma unroll
            for (int j = 0; j < 8; ++j) {
                float xf = (float)xv[j];
                aq += (float)wq[j] * xf; ak += (float)wk[j] * xf; av += (float)wv[j] * xf;
            }
        }
        qs[io][l] = (bf16)aq; ks[io][l] = (bf16)ak; vt[l][io] = (bf16)av;
    }
    __syncthreads();
    // ---- S = q @ k^T over l (logits into Ps)
    for (int s = 0; s < 16; ++s) {
        int o = s * 256 + tid; int i = o >> 6, j = o & 63;
        float acc = 0.f;
        for (int c8 = 0; c8 < 12; ++c8) {
            bf16x8 qv = *(const bf16x8*)&qs[i][c8 * 8];
            bf16x8 kv = *(const bf16x8*)&ks[j][c8 * 8];
            #pragma unroll
            for (int t = 0; t < 8; ++t) acc += (float)qv[t] * (float)kv[t];
        }
        Ps[i][j] = (bf16)acc;
    }
    __syncthreads();
    // ---- softmax rows (wave 0), logits/sqrt(8)
    if (tid < 64) {
        const float inv_kd = 0.35355339059327379f;
        int i = tid; float m = -1e30f;
        for (int j = 0; j < 64; ++j) m = fmaxf(m, (float)Ps[i][j]);
        float ssum = 0.f;
        for (int j = 0; j < 64; ++j) { float e = __expf(((float)Ps[i][j] - m) * inv_kd); ssum += e; Ps[i][j] = (bf16)e; }
        float rc = 1.f / ssum;
        for (int j = 0; j < 64; ++j) Ps[i][j] = (bf16)((float)Ps[i][j] * rc);
    }
    __syncthreads();
    // ---- line = P @ v
    for (int s = 0; s < 24; ++s) {
        int o = s * 256 + tid; int i = o / 96, l = o - i * 96;
        float acc = 0.f;
        for (int c8 = 0; c8 < 8; ++c8) {
            bf16x8 pv = *(const bf16x8*)&Ps[i][c8 * 8];
            bf16x8 vv = *(const bf16x8*)&vt[l][c8 * 8];
            #pragma unroll
            for (int t = 0; t < 8; ++t) acc += (float)pv[t] * (float)vv[t];
        }
        lf[i][l] = acc;
    }
    __syncthreads();
    // ---- residual (fp32 x) + LayerNorm over l; coalesced fp32 store
    if (tid < 64) {
        int i = tid;
        float s1 = 0.f, s2 = 0.f;
        for (int l = 0; l < 96; ++l) {
            float h = xp[l * 64 + i] + (lf[i][l] * hscale + hbias);
            s1 += h; s2 += h * h;
        }
        float mean = s1 * (1.f / 96.f);
        float var = s2 * (1.f / 96.f) - mean * mean;
        float rs = rsqrtf(var + 1e-5f);
        float* dst = tout + (size_t)bn * 6144;
        for (int l = 0; l < 96; ++l) {
            float h = xp[l * 64 + i] + (lf[i][l] * hscale + hbias);
            dst[l * 64 + i] = (h - mean) * rs * lng[l] + lnb[l];
        }
    }
}

// ---------------- K2: space attention (MFMA), one block per (b,l); writes s_T directly ----------------
// Numerics identical to the round-4 VALU version: bf16 operands, fp32 accumulation,
// bf16 at qc/kc/vtc/Ps, fp32 sac, same bias/scale points. No LDS overlays for tt.
__global__ __launch_bounds__(256) void k_att_space(
    const float* __restrict__ x, const bf16* __restrict__ wsb,
    const float* __restrict__ qb, const float* __restrict__ kb, const float* __restrict__ vb,
    const float* __restrict__ hw, const float* __restrict__ hb,
    bf16* __restrict__ sT)
{
    extern __shared__ char smem[];
    bf16 (*xs)[520] = (bf16(*)[520])smem;               // 66,560 B  xs[ie][n]
    bf16 (*qc)[72]  = (bf16(*)[72])(smem + 66560);      //  9,216 B  q chunk [i][n'] (vtc overlay)
    bf16 (*kc)[72]  = (bf16(*)[72])(smem + 75776);      //  9,216 B  k chunk [j][n']
    bf16 (*wt)[136] = (bf16(*)[136])(smem + 84992);     // 17,408 B  weight tile [64][128]
    bf16 (*Ps)[72]  = (bf16(*)[72])(smem + 102400);     //  9,216 B  P [i][j]
    bf16 (*tt)[72]  = (bf16(*)[72])(smem + 111616);     //  9,216 B  out transpose tile (own region)
    bf16 (*vtc)[72] = qc;                               // total 120,832 B

    const int tid = threadIdx.x;
    const int b = blockIdx.x / 96, l = blockIdx.x % 96;
    const int lane = tid & 63, w = tid >> 6, lrow = lane & 15, lgrp = lane >> 4;
    const int row0 = w * 16;

    {   // load x slice -> xs[ie][n], bf16
        const float* xb = x + ((size_t)b * 512 * 96 + l) * 64;
        for (int idx = tid; idx < 512 * 64; idx += 256) {
            int n = idx >> 6, ie = idx & 63;
            xs[ie][n] = (bf16)xb[(size_t)n * 6144 + ie];
        }
    }
    float hscale = hw[0] + hw[1] + hw[2] + hw[3] + hw[4] + hw[5] + hw[6] + hw[7];
    float hbias = hb[0];
    __syncthreads();

    const bf16* Wq = wsb + W_SQ;
    const bf16* Wk = wsb + W_SK;
    const bf16* Wv = wsb + W_SV;

    f32x4 sac[4];
    for (int jf = 0; jf < 4; ++jf) sac[jf] = (f32x4){0.f, 0.f, 0.f, 0.f};

    for (int nqc = 0; nqc < 8; ++nqc) {
        // ---- q chunk: qc[ie][n'-local], contraction K = 512 in 4 tiles of 128
        {
            f32x4 pacc[4];
            for (int cf = 0; cf < 4; ++cf) pacc[cf] = (f32x4){0.f, 0.f, 0.f, 0.f};
            for (int kt = 0; kt < 4; ++kt) {
                for (int idx = tid; idx < 4096; idx += 256) {
                    int rr = idx >> 6, j = idx & 63;
                    *(uint*)&wt[rr][2 * j] = *(const uint*)(Wq + (size_t)(nqc * 64 + rr) * 512 + kt * 128 + 2 * j);
                }
                __syncthreads();
                for (int ks_ = 0; ks_ < 4; ++ks_) {
                    bf16x8 a = *(const bf16x8*)&xs[row0 + lrow][kt * 128 + ks_ * 32 + lgrp * 8];
                    for (int cf = 0; cf < 4; ++cf)
                        pacc[cf] = MFMA16(a, *(const bf16x8*)&wt[cf * 16 + lrow][ks_ * 32 + lgrp * 8], pacc[cf]);
                }
                __syncthreads();
            }
            for (int cf = 0; cf < 4; ++cf)
                for (int r = 0; r < 4; ++r) {
                    int i = row0 + lgrp * 4 + r, nl = cf * 16 + lrow;
                    qc[i][nl] = (bf16)(pacc[cf][r] + qb[nqc * 64 + nl]);
                }
        }
        // ---- k chunk
        {
            f32x4 pacc[4];
            for (int cf = 0; cf < 4; ++cf) pacc[cf] = (f32x4){0.f, 0.f, 0.f, 0.f};
            for (int kt = 0; kt < 4; ++kt) {
                for (int idx = tid; idx < 4096; idx += 256) {
                    int rr = idx >> 6, j = idx & 63;
                    *(uint*)&wt[rr][2 * j] = *(const uint*)(Wk + (size_t)(nqc * 64 + rr) * 512 + kt * 128 + 2 * j);
                }
                __syncthreads();
                for (int ks_ = 0; ks_ < 4; ++ks_) {
                    bf16x8 a = *(const bf16x8*)&xs[row0 + lrow][kt * 128 + ks_ * 32 + lgrp * 8];
                    for (int cf = 0; cf < 4; ++cf)
                        pacc[cf] = MFMA16(a, *(const bf16x8*)&wt[cf * 16 + lrow][ks_ * 32 + lgrp * 8], pacc[cf]);
                }
                __syncthreads();
            }
            for (int cf = 0; cf < 4; ++cf)
                for (int r = 0; r < 4; ++r) {
                    int i = row0 + lgrp * 4 + r, nl = cf * 16 + lrow;
                    kc[i][nl] = (bf16)(pacc[cf][r] + kb[nqc * 64 + nl]);
                }
        }
        __syncthreads();   // qc/kc visible to all warps
        // ---- S += q_c @ k_c^T (contraction over this n' chunk)
        for (int kk = 0; kk < 2; ++kk) {
            bf16x8 a = *(const bf16x8*)&qc[row0 + lrow][kk * 32 + lgrp * 8];
            for (int jf = 0; jf < 4; ++jf)
                sac[jf] = MFMA16(a, *(const bf16x8*)&kc[jf * 16 + lrow][kk * 32 + lgrp * 8], sac[jf]);
        }
        __syncthreads();   // S reads done before next chunk overwrites qc/kc
    }
    // ---- softmax over j (rows i), logits = S/8; fp32 sac
    {
        float pr[4][4], rcp[4];
        for (int r = 0; r < 4; ++r) {
            float m = fmaxf(fmaxf(sac[0][r], sac[1][r]), fmaxf(sac[2][r], sac[3][r]));
            for (int msk = 1; msk < 16; msk <<= 1) m = fmaxf(m, __shfl_xor(m, msk, 64));
            float s = 0.f;
            for (int jf = 0; jf < 4; ++jf) { pr[jf][r] = __expf((sac[jf][r] - m) * 0.125f); s += pr[jf][r]; }
            for (int msk = 1; msk < 16; msk <<= 1) s += __shfl_xor(s, msk, 64);
            rcp[r] = 1.f / s;
        }
        for (int jf = 0; jf < 4; ++jf)
            for (int r = 0; r < 4; ++r)
                Ps[row0 + lgrp * 4 + r][jf * 16 + lrow] = (bf16)(pr[jf][r] * rcp[r]);
    }
    __syncthreads();
    // ---- PV per 64-col chunk; fused transpose store to s_T[b][n][l][ie]
    for (int nc = 0; nc < 8; ++nc) {
        {   // v chunk -> vtc[n-local][j] (transposed), + bias  (vtc overlays qc; qc dead)
            f32x4 pacc[4];
            for (int cf = 0; cf < 4; ++cf) pacc[cf] = (f32x4){0.f, 0.f, 0.f, 0.f};
            for (int kt = 0; kt < 4; ++kt) {
                for (int idx = tid; idx < 4096; idx += 256) {
                    int rr = idx >> 6, j = idx & 63;
                    *(uint*)&wt[rr][2 * j] = *(const uint*)(Wv + (size_t)(nc * 64 + rr) * 512 + kt * 128 + 2 * j);
                }
                __syncthreads();
                for (int ks_ = 0; ks_ < 4; ++ks_) {
                    bf16x8 a = *(const bf16x8*)&xs[row0 + lrow][kt * 128 + ks_ * 32 + lgrp * 8];
                    for (int cf = 0; cf < 4; ++cf)
                        pacc[cf] = MFMA16(a, *(const bf16x8*)&wt[cf * 16 + lrow][ks_ * 32 + lgrp * 8], pacc[cf]);
                }
                __syncthreads();
            }
            for (int cf = 0; cf < 4; ++cf)
                for (int r = 0; r < 4; ++r) {
                    int j = row0 + lgrp * 4 + r, nl = cf * 16 + lrow;
                    vtc[nl][j] = (bf16)(pacc[cf][r] + vb[nc * 64 + nl]);
                }
        }
        __syncthreads();   // vtc visible
        // ---- line chunk = P @ v_c -> tt[n-local][i], scale + head bias
        f32x4 oc[4];
        for (int cf = 0; cf < 4; ++cf) oc[cf] = (f32x4){0.f, 0.f, 0.f, 0.f};
        for (int kk = 0; kk < 2; ++kk) {
            bf16x8 a = *(const bf16x8*)&Ps[row0 + lrow][kk * 32 + lgrp * 8];
            for (int cf = 0; cf < 4; ++cf)
                oc[cf] = MFMA16(a, *(const bf16x8*)&vtc[cf * 16 + lrow][kk * 32 + lgrp * 8], oc[cf]);
        }
        for (int cf = 0; cf < 4; ++cf)
            for (int r = 0; r < 4; ++r) {
                int i = row0 + lgrp * 4 + r, nl = cf * 16 + lrow;
                tt[nl][i] = (bf16)(oc[cf][r] * hscale + hbias);
            }
        __syncthreads();   // tt complete; also fences vtc reads before next nc overwrites
        for (int idx = tid; idx < 2048; idx += 256) {
            int n = idx >> 5, p = idx & 31;
            *(uint*)(sT + ((size_t)(b * 512 + nc * 64 + n) * 96 + l) * 64 + 2 * p) = *(const uint*)&tt[n][2 * p];
        }
        __syncthreads();   // stores done before tt rewritten
    }
}

// ---------------- K3: cross attention + LN (VALU fp32 compute), one block per (b,n) ----------------
__global__ __launch_bounds__(256) void k_att_cross(
    const float* __restrict__ tin, const bf16* __restrict__ sin, const bf16* __restrict__ wsb,
    const float* __restrict__ qb, const float* __restrict__ kb, const float* __restrict__ vb,
    const float* __restrict__ lng, const float* __restrict__ lnb,
    const float* __restrict__ hw, const float* __restrict__ hb,
    bf16* __restrict__ cout)
{
    // r0 [0,26624):      qs[64][104], ks[64][104] -> lf[64][100] fp32
    // r1 [26624,40448):  ts[96][72] -> Ps[64][72] -> cs[64][104]
    // r2 [40448,54272):  ss[96][72] -> vt[96][72]
    __shared__ __align__(16) char smem_[54272];
    bf16  (*qs)[104] = (bf16(*)[104])smem_;
    bf16  (*ks)[104] = (bf16(*)[104])(smem_ + 13312);
    float (*lf)[100] = (float(*)[100])smem_;
    bf16  (*ts)[72]  = (bf16(*)[72])(smem_ + 26624);
    bf16  (*Ps)[72]  = (bf16(*)[72])(smem_ + 26624);
    bf16  (*cs)[104] = (bf16(*)[104])(smem_ + 26624);
    bf16  (*ss)[72]  = (bf16(*)[72])(smem_ + 40448);
    bf16  (*vt)[72]  = (bf16(*)[72])(smem_ + 40448);

    const int tid = threadIdx.x;
    const int bn = blockIdx.x;

    const float* tf = tin + (size_t)bn * 6144;
    const uint* ssrc = (const uint*)(sin + (size_t)bn * 6144);
    for (int idx = tid; idx < 3072; idx += 256) {
        int l = idx >> 5, p = idx & 31;
        *(uint*)&ss[l][2 * p] = ssrc[idx];
    }
    for (int idx = tid; idx < 6144; idx += 256) ts[idx / 64][idx & 63] = (bf16)tf[idx];
    float hscale = hw[0] + hw[1] + hw[2] + hw[3] + hw[4] + hw[5] + hw[6] + hw[7];
    float hbias = hb[0];
    __syncthreads();

    const bf16* Wq = wsb + W_CQ;
    const bf16* Wk = wsb + W_CK;
    const bf16* Wv = wsb + W_CV;
    // ---- q conv from s slice
    for (int s = 0; s < 24; ++s) {
        int o = s * 256 + tid; int io = o / 96, l = o - io * 96;
        float aq = qb[io];
        for (int c8 = 0; c8 < 8; ++c8) {
            bf16x8 xv = *(const bf16x8*)&ss[l][c8 * 8];
            bf16x8 wq = *(const bf16x8*)(Wq + io * 64 + c8 * 8);
            #pragma unroll
            for (int j = 0; j < 8; ++j) aq += (float)wq[j] * (float)xv[j];
        }
        qs[io][l] = (bf16)aq;
    }
    __syncthreads();   // ss dead; vt may be written
    // ---- k, v convs from t slice (v transposed into vt over ss)
    for (int s = 0; s < 24; ++s) {
        int o = s * 256 + tid; int io = o / 96, l = o - io * 96;
        float ak = kb[io], av = vb[io];
        for (int c8 = 0; c8 < 8; ++c8) {
            bf16x8 xv = *(const bf16x8*)&ts[l][c8 * 8];
            bf16x8 wk = *(const bf16x8*)(Wk + io * 64 + c8 * 8);
            bf16x8 wv = *(const bf16x8*)(Wv + io * 64 + c8 * 8);
            #pragma unroll
            for (int j = 0; j < 8; ++j) {
                float xf = (float)xv[j];
                ak += (float)wk[j] * xf; av += (float)wv[j] * xf;
            }
        }
        ks[io][l] = (bf16)ak; vt[l][io] = (bf16)av;
    }
    __syncthreads();   // ts dead after this point (residual uses tf global); Ps may be written
    // ---- S = q @ k^T over l
    for (int s = 0; s < 16; ++s) {
        int o = s * 256 + tid; int i = o >> 6, j = o & 63;
        float acc = 0.f;
        for (int c8 = 0; c8 < 12; ++c8) {
            bf16x8 qv = *(const bf16x8*)&qs[i][c8 * 8];
            bf16x8 kv = *(const bf16x8*)&ks[j][c8 * 8];
            #pragma unroll
            for (int t = 0; t < 8; ++t) acc += (float)qv[t] * (float)kv[t];
        }
        Ps[i][j] = (bf16)acc;
    }
    __syncthreads();
    // ---- softmax rows (wave 0)
    if (tid < 64) {
        const float inv_kd = 0.35355339059327379f;
        int i = tid; float m = -1e30f;
        for (int j = 0; j < 64; ++j) m = fmaxf(m, (float)Ps[i][j]);
        float ssum = 0.f;
        for (int j = 0; j < 64; ++j) { float e = __expf(((float)Ps[i][j] - m) * inv_kd); ssum += e; Ps[i][j] = (bf16)e; }
        float rc = 1.f / ssum;
        for (int j = 0; j < 64; ++j) Ps[i][j] = (bf16)((float)Ps[i][j] * rc);
    }
    __syncthreads();
    // ---- line = P @ v
    for (int s = 0; s < 24; ++s) {
        int o = s * 256 + tid; int i = o / 96, l = o - i * 96;
        float acc = 0.f;
        for (int c8 = 0; c8 < 8; ++c8) {
            bf16x8 pv = *(const bf16x8*)&Ps[i][c8 * 8];
            bf16x8 vv = *(const bf16x8*)&vt[l][c8 * 8];
            #pragma unroll
            for (int t = 0; t < 8; ++t) acc += (float)pv[t] * (float)vv[t];
        }
        lf[i][l] = acc;
    }
    __syncthreads();
    // ---- residual (fp32 t_out) + LN over l -> cs[i][l] (Ps region dead)
    if (tid < 64) {
        int i = tid;
        float s1 = 0.f, s2 = 0.f;
        for (int l = 0; l < 96; ++l) {
            float h = tf[l * 64 + i] + (lf[i][l] * hscale + hbias);
            s1 += h; s2 += h * h;
        }
        float mean = s1 * (1.f / 96.f);
        float var = s2 * (1.f / 96.f) - mean * mean;
        float rs = rsqrtf(var + 1e-5f);
        for (int l = 0; l < 96; ++l) {
            float h = tf[l * 64 + i] + (lf[i][l] * hscale + hbias);
            cs[i][l] = (bf16)((h - mean) * rs * lng[l] + lnb[l]);
        }
    }
    __syncthreads();
    uint* dst = (uint*)(cout + (size_t)bn * 6144);
    for (int idx = tid; idx < 3072; idx += 256) {
        int i = idx / 48, p = idx % 48;
        dst[idx] = *(const uint*)&cs[i][2 * p];
    }
}

// ---------------- K4: final GEMM [8192 x 96 x 6144] (MFMA, proven) ----------------
__global__ __launch_bounds__(256) void k_final(
    const bf16* __restrict__ cin, const bf16* __restrict__ wsb,
    const float* __restrict__ ob, float* __restrict__ out)
{
    __shared__ bf16 At[64][136];
    __shared__ bf16 Wt[96][136];
    const int tid = threadIdx.x;
    const int r0 = blockIdx.x * 64;
    const int lane = tid & 63, w = tid >> 6, lrow = lane & 15, lgrp = lane >> 4;
    const int row0 = w * 16;
    const bf16* Wo = wsb + W_OW;

    f32x4 acc[6];
    for (int cf = 0; cf < 6; ++cf) acc[cf] = (f32x4){0.f, 0.f, 0.f, 0.f};
    for (int kt = 0; kt < 48; ++kt) {
        for (int idx = tid; idx < 4096; idx += 256) {
            int rr = idx >> 6, j = idx & 63;
            *(uint*)&At[rr][2 * j] = *(const uint*)(cin + (size_t)(r0 + rr) * 6144 + kt * 128 + 2 * j);
        }
        for (int idx = tid; idx < 6144; idx += 256) {
            int rr = idx >> 6, j = idx & 63;
            *(uint*)&Wt[rr][2 * j] = *(const uint*)(Wo + (size_t)rr * 6144 + kt * 128 + 2 * j);
        }
        __syncthreads();
        for (int ks_ = 0; ks_ < 4; ++ks_) {
            bf16x8 a = *(const bf16x8*)&At[row0 + lrow][ks_ * 32 + lgrp * 8];
            for (int cf = 0; cf < 6; ++cf)
                acc[cf] = MFMA16(a, *(const bf16x8*)&Wt[cf * 16 + lrow][ks_ * 32 + lgrp * 8], acc[cf]);
        }
        __syncthreads();
    }
    for (int cf = 0; cf < 6; ++cf)
        for (int r = 0; r < 4; ++r) {
            int row = r0 + row0 + lgrp * 4 + r, col = cf * 16 + lrow;
            out[(size_t)row * 96 + col] = acc[cf][r] + ob[col];
        }
}

// ---------------- host ----------------
extern "C" void kernel_launch(void* const* d_in, const int* in_sizes, int n_in,
                              void* d_out, int out_size, void* d_ws, size_t ws_size,
                              hipStream_t stream)
{
    const float* x = (const float*)d_in[0];
    const float* tq_w = (const float*)d_in[1];  const float* tq_b = (const float*)d_in[2];
    const float* tk_w = (const float*)d_in[3];  const float* tk_b = (const float*)d_in[4];
    const float* tv_w = (const float*)d_in[5];  const float* tv_b = (const float*)d_in[6];
    const float* t_ln_w = (const float*)d_in[7];  const float* t_ln_b = (const float*)d_in[8];
    const float* t_hw = (const float*)d_in[9];  const float* t_hb = (const float*)d_in[10];
    const float* sq_w = (const float*)d_in[11]; const float* sq_b = (const float*)d_in[12];
    const float* sk_w = (const float*)d_in[13]; const float* sk_b = (const float*)d_in[14];
    const float* sv_w = (const float*)d_in[15]; const float* sv_b = (const float*)d_in[16];
    const float* s_hw = (const float*)d_in[17]; const float* s_hb = (const float*)d_in[18];
    const float* cq_w = (const float*)d_in[19]; const float* cq_b = (const float*)d_in[20];
    const float* ck_w = (const float*)d_in[21]; const float* ck_b = (const float*)d_in[22];
    const float* cv_w = (const float*)d_in[23]; const float* cv_b = (const float*)d_in[24];
    const float* c_ln_w = (const float*)d_in[25]; const float* c_ln_b = (const float*)d_in[26];
    const float* c_hw = (const float*)d_in[27]; const float* c_hb = (const float*)d_in[28];
    const float* out_w = (const float*)d_in[29]; const float* out_b = (const float*)d_in[30];

    char* ws = (char*)d_ws;
    bf16*  wsb  = (bf16*)(ws + OFF_WSB);
    float* tout = (float*)(ws + OFF_TOUT);
    bf16*  sT   = (bf16*)(ws + OFF_ST);
    bf16*  cout = (bf16*)(ws + OFF_COUT);

    hipFuncSetAttribute((const void*)k_att_space, hipFuncAttributeMaxDynamicSharedMemorySize, 120832);

    k_cvt<<<W_END / 256, 256, 0, stream>>>(sq_w, sk_w, sv_w, tq_w, tk_w, tv_w, cq_w, ck_w, cv_w, out_w, wsb);
    k_att_time<<<8192, 256, 0, stream>>>(x, wsb, tq_b, tk_b, tv_b, t_ln_w, t_ln_b, t_hw, t_hb, tout);
    k_att_space<<<1536, 256, 120832, stream>>>(x, wsb, sq_b, sk_b, sv_b, s_hw, s_hb, sT);
    k_att_cross<<<8192, 256, 0, stream>>>(tout, sT, wsb, cq_b, ck_b, cv_b, c_ln_w, c_ln_b, c_hw, c_hb, cout);
    k_final<<<128, 256, 0, stream>>>(cout, wsb, out_b, (float*)d_out);
}